// Round 1
// baseline (542.698 us; speedup 1.0000x reference)
//
#include <hip/hip_runtime.h>

// Problem constants (B,S,D,N,H) = (4,1024,768,12,64), all fp32.
constexpr int B_ = 4;
constexpr int S_ = 1024;
constexpr int D_ = 768;
constexpr int N_ = 12;
constexpr int H_ = 64;
constexpr int BNSH = B_ * N_ * S_ * H_;       // 3,145,728 elems per tensor
constexpr float SCALE = 0.125f;               // 1/sqrt(64)
constexpr float IGNORE = -100000.0f;

__device__ __forceinline__ float f4c(const float4 v, int i) {
    return i == 0 ? v.x : i == 1 ? v.y : i == 2 ? v.z : v.w;
}

// ---------------------------------------------------------------------------
// Kernel 1: QKV projection.  C[m, mat*768 + n*64 + h] = x[m,:] . W[n,:,h]
// Tile 64x64, K-tile 64, 256 threads, 4x4 micro-tile per thread.
// Output layout: qkv[mat][b][n][s][h]  (mat 0=Q,1=K,2=V), each [B,N,S,H].
// ---------------------------------------------------------------------------
__global__ __launch_bounds__(256) void qkv_kernel(
    const float* __restrict__ x,
    const float* __restrict__ wq, const float* __restrict__ wk,
    const float* __restrict__ wv,
    const float* __restrict__ bq, const float* __restrict__ bk,
    const float* __restrict__ bv,
    float* __restrict__ qkv)
{
    __shared__ __align__(16) float As[64][68];
    __shared__ __align__(16) float Bs[64][68];

    const int mt  = blockIdx.x;            // 0..63  (row tile of 64)
    const int ct  = blockIdx.y;            // 0..35  (matrix*12 + head)
    const int mat = ct / N_;
    const int n   = ct % N_;
    const float* wbase = (mat == 0 ? wq : (mat == 1 ? wk : wv)) + (size_t)n * D_ * H_;
    const float* bias  = (mat == 0 ? bq : (mat == 1 ? bk : bv)) + n * H_;
    float* obase = qkv + (size_t)mat * BNSH;

    const int tid = threadIdx.x;
    const int ty  = tid >> 4;              // 0..15  row group
    const int tx  = tid & 15;              // 0..15  col group (cols tx*4..tx*4+3)
    const int m0  = mt * 64;
    const int lr  = tid >> 4, lc4 = tid & 15;

    float acc[4][4] = {};

    for (int kt = 0; kt < 12; ++kt) {
        __syncthreads();
        #pragma unroll
        for (int ii = 0; ii < 4; ++ii) {
            int row = lr + 16 * ii;
            *(float4*)&As[row][lc4 * 4] =
                *(const float4*)&x[(size_t)(m0 + row) * D_ + kt * 64 + lc4 * 4];
            *(float4*)&Bs[row][lc4 * 4] =
                *(const float4*)&wbase[(size_t)(kt * 64 + row) * H_ + lc4 * 4];
        }
        __syncthreads();

        #pragma unroll
        for (int d4 = 0; d4 < 16; ++d4) {
            float4 a4[4];
            #pragma unroll
            for (int i = 0; i < 4; ++i)
                a4[i] = *(const float4*)&As[ty + 16 * i][d4 * 4];
            #pragma unroll
            for (int dd = 0; dd < 4; ++dd) {
                float4 bv4 = *(const float4*)&Bs[d4 * 4 + dd][tx * 4];
                #pragma unroll
                for (int i = 0; i < 4; ++i) {
                    float av = f4c(a4[i], dd);
                    acc[i][0] += av * bv4.x;
                    acc[i][1] += av * bv4.y;
                    acc[i][2] += av * bv4.z;
                    acc[i][3] += av * bv4.w;
                }
            }
        }
    }

    float4 b4 = *(const float4*)&bias[tx * 4];
    #pragma unroll
    for (int i = 0; i < 4; ++i) {
        int m  = m0 + ty + 16 * i;
        int bb = m >> 10;
        int ss = m & 1023;
        float4 o4;
        o4.x = acc[i][0] + b4.x;
        o4.y = acc[i][1] + b4.y;
        o4.z = acc[i][2] + b4.z;
        o4.w = acc[i][3] + b4.w;
        *(float4*)&obase[(((size_t)bb * N_ + n) * S_ + ss) * H_ + tx * 4] = o4;
    }
}

// ---------------------------------------------------------------------------
// Kernel 2: causal flash attention per (b, n, q-tile of 64). fp32.
// z layout: [B, S, N, H] so out-projection is a plain row-major GEMM.
// ---------------------------------------------------------------------------
__global__ __launch_bounds__(256) void attn_kernel(
    const float* __restrict__ qkv, float* __restrict__ z)
{
    __shared__ __align__(16) float Qs[64][68];
    __shared__ __align__(16) float Ks[64][68];
    __shared__ __align__(16) float Vs[64][68];
    __shared__ __align__(16) float Ps[64][68];
    __shared__ float row_m[64], row_l[64], row_a[64];
    __shared__ float seg[4][64];

    const int bid = blockIdx.x;
    const int qt  = bid & 15;
    const int n   = (bid >> 4) % N_;
    const int b   = bid / (16 * N_);

    const float* Qg = qkv + (size_t)(b * N_ + n) * S_ * H_;
    const float* Kg = Qg + BNSH;
    const float* Vg = Qg + 2 * (size_t)BNSH;

    const int tid = threadIdx.x;
    const int ty  = tid >> 4, tx = tid & 15;
    const int lr  = tid >> 4, lc4 = tid & 15;
    const int q0  = qt * 64;

    #pragma unroll
    for (int ii = 0; ii < 4; ++ii) {
        int row = lr + 16 * ii;
        *(float4*)&Qs[row][lc4 * 4] =
            *(const float4*)&Qg[(size_t)(q0 + row) * H_ + lc4 * 4];
    }
    if (tid < 64) { row_m[tid] = -1e30f; row_l[tid] = 0.f; }

    float o[4][4] = {};

    for (int kt = 0; kt <= qt; ++kt) {
        __syncthreads();   // previous iter's PV done; safe to overwrite K/V
        #pragma unroll
        for (int ii = 0; ii < 4; ++ii) {
            int row = lr + 16 * ii;
            *(float4*)&Ks[row][lc4 * 4] =
                *(const float4*)&Kg[(size_t)(kt * 64 + row) * H_ + lc4 * 4];
            *(float4*)&Vs[row][lc4 * 4] =
                *(const float4*)&Vg[(size_t)(kt * 64 + row) * H_ + lc4 * 4];
        }
        __syncthreads();

        // --- scores: q = ty+16i, k = tx+16j ---
        float sc[4][4] = {};
        #pragma unroll
        for (int d4 = 0; d4 < 16; ++d4) {
            float4 a4[4], k4[4];
            #pragma unroll
            for (int i = 0; i < 4; ++i)
                a4[i] = *(const float4*)&Qs[ty + 16 * i][d4 * 4];
            #pragma unroll
            for (int j = 0; j < 4; ++j)
                k4[j] = *(const float4*)&Ks[tx + 16 * j][d4 * 4];
            #pragma unroll
            for (int i = 0; i < 4; ++i)
                #pragma unroll
                for (int j = 0; j < 4; ++j)
                    sc[i][j] += a4[i].x * k4[j].x + a4[i].y * k4[j].y
                              + a4[i].z * k4[j].z + a4[i].w * k4[j].w;
        }
        #pragma unroll
        for (int i = 0; i < 4; ++i)
            #pragma unroll
            for (int j = 0; j < 4; ++j) {
                float v = sc[i][j] * SCALE;
                if (kt == qt && (tx + 16 * j) > (ty + 16 * i)) v = IGNORE;
                Ps[ty + 16 * i][tx + 16 * j] = v;
            }
        __syncthreads();

        // --- online softmax ---
        {   // per-segment max: 256 threads cover 64 rows x 4 segments of 16
            int qq = tid >> 2, sg = tid & 3;
            float mx = -1e30f;
            #pragma unroll
            for (int k = 0; k < 16; ++k) mx = fmaxf(mx, Ps[qq][sg * 16 + k]);
            seg[sg][qq] = mx;
        }
        __syncthreads();
        if (tid < 64) {
            float mt_ = fmaxf(fmaxf(seg[0][tid], seg[1][tid]),
                              fmaxf(seg[2][tid], seg[3][tid]));
            float m_old = row_m[tid];
            float m_new = fmaxf(m_old, mt_);
            row_a[tid] = __expf(m_old - m_new);   // 0 when m_old == -1e30
            row_m[tid] = m_new;
        }
        __syncthreads();
        {   // exponentiate + per-segment sums
            int qq = tid >> 2, sg = tid & 3;
            float m_new = row_m[qq];
            float sum = 0.f;
            #pragma unroll
            for (int k = 0; k < 16; ++k) {
                float p = __expf(Ps[qq][sg * 16 + k] - m_new);
                Ps[qq][sg * 16 + k] = p;
                sum += p;
            }
            seg[sg][qq] = sum;
        }
        __syncthreads();
        if (tid < 64)
            row_l[tid] = row_l[tid] * row_a[tid]
                       + seg[0][tid] + seg[1][tid] + seg[2][tid] + seg[3][tid];

        // --- PV accumulate: q = ty+16i, h = tx*4+j ---
        float al[4];
        #pragma unroll
        for (int i = 0; i < 4; ++i) al[i] = row_a[ty + 16 * i];
        #pragma unroll
        for (int i = 0; i < 4; ++i)
            #pragma unroll
            for (int j = 0; j < 4; ++j) o[i][j] *= al[i];

        #pragma unroll
        for (int k4 = 0; k4 < 16; ++k4) {
            float4 p4[4];
            #pragma unroll
            for (int i = 0; i < 4; ++i)
                p4[i] = *(const float4*)&Ps[ty + 16 * i][k4 * 4];
            #pragma unroll
            for (int kk = 0; kk < 4; ++kk) {
                float4 vv = *(const float4*)&Vs[k4 * 4 + kk][tx * 4];
                #pragma unroll
                for (int i = 0; i < 4; ++i) {
                    float pv = f4c(p4[i], kk);
                    o[i][0] += pv * vv.x;
                    o[i][1] += pv * vv.y;
                    o[i][2] += pv * vv.z;
                    o[i][3] += pv * vv.w;
                }
            }
        }
    }
    __syncthreads();   // ensure row_l final

    #pragma unroll
    for (int i = 0; i < 4; ++i) {
        int q = ty + 16 * i;
        float linv = 1.0f / row_l[q];
        float4 zo;
        zo.x = o[i][0] * linv;
        zo.y = o[i][1] * linv;
        zo.z = o[i][2] * linv;
        zo.w = o[i][3] * linv;
        *(float4*)&z[(((size_t)b * S_ + q0 + q) * N_ + n) * H_ + tx * 4] = zo;
    }
}

// ---------------------------------------------------------------------------
// Kernel 3: output projection. out[m,d] = z[m,:] . W_O_flat[:,d] + b_O[d]
// z is [4096, 768] row-major (col = n*64+h); W_O [N,H,D] flattens to [768,768].
// ---------------------------------------------------------------------------
__global__ __launch_bounds__(256) void out_kernel(
    const float* __restrict__ zin, const float* __restrict__ wo,
    const float* __restrict__ bo, float* __restrict__ out)
{
    __shared__ __align__(16) float As[64][68];
    __shared__ __align__(16) float Bs[64][68];

    const int mt = blockIdx.x;   // 0..63
    const int ct = blockIdx.y;   // 0..11
    const int tid = threadIdx.x;
    const int ty  = tid >> 4, tx = tid & 15;
    const int lr  = tid >> 4, lc4 = tid & 15;
    const int m0  = mt * 64, c0 = ct * 64;

    float acc[4][4] = {};

    for (int kt = 0; kt < 12; ++kt) {
        __syncthreads();
        #pragma unroll
        for (int ii = 0; ii < 4; ++ii) {
            int row = lr + 16 * ii;
            *(float4*)&As[row][lc4 * 4] =
                *(const float4*)&zin[(size_t)(m0 + row) * D_ + kt * 64 + lc4 * 4];
            *(float4*)&Bs[row][lc4 * 4] =
                *(const float4*)&wo[(size_t)(kt * 64 + row) * D_ + c0 + lc4 * 4];
        }
        __syncthreads();

        #pragma unroll
        for (int d4 = 0; d4 < 16; ++d4) {
            float4 a4[4];
            #pragma unroll
            for (int i = 0; i < 4; ++i)
                a4[i] = *(const float4*)&As[ty + 16 * i][d4 * 4];
            #pragma unroll
            for (int dd = 0; dd < 4; ++dd) {
                float4 bv4 = *(const float4*)&Bs[d4 * 4 + dd][tx * 4];
                #pragma unroll
                for (int i = 0; i < 4; ++i) {
                    float av = f4c(a4[i], dd);
                    acc[i][0] += av * bv4.x;
                    acc[i][1] += av * bv4.y;
                    acc[i][2] += av * bv4.z;
                    acc[i][3] += av * bv4.w;
                }
            }
        }
    }

    float4 b4 = *(const float4*)&bo[c0 + tx * 4];
    #pragma unroll
    for (int i = 0; i < 4; ++i) {
        int m = m0 + ty + 16 * i;
        float4 o4;
        o4.x = acc[i][0] + b4.x;
        o4.y = acc[i][1] + b4.y;
        o4.z = acc[i][2] + b4.z;
        o4.w = acc[i][3] + b4.w;
        *(float4*)&out[(size_t)m * D_ + c0 + tx * 4] = o4;
    }
}

// ---------------------------------------------------------------------------
extern "C" void kernel_launch(void* const* d_in, const int* in_sizes, int n_in,
                              void* d_out, int out_size, void* d_ws, size_t ws_size,
                              hipStream_t stream)
{
    const float* x  = (const float*)d_in[0];
    const float* wq = (const float*)d_in[1];
    const float* wk = (const float*)d_in[2];
    const float* wv = (const float*)d_in[3];
    const float* wo = (const float*)d_in[4];
    const float* bq = (const float*)d_in[5];
    const float* bk = (const float*)d_in[6];
    const float* bv = (const float*)d_in[7];
    const float* bo = (const float*)d_in[8];
    float* out = (float*)d_out;

    float* ws  = (float*)d_ws;
    float* qkv = ws;                          // 3 * BNSH floats (Q,K,V)
    float* z   = ws + 3 * (size_t)BNSH;       // BNSH floats

    qkv_kernel<<<dim3(64, 36), 256, 0, stream>>>(x, wq, wk, wv, bq, bk, bv, qkv);
    attn_kernel<<<dim3(B_ * N_ * 16), 256, 0, stream>>>(qkv, z);
    out_kernel<<<dim3(64, 12), 256, 0, stream>>>(z, wo, bo, out);
}

// Round 2
// 184.521 us; speedup vs baseline: 2.9411x; 2.9411x over previous
//
#include <hip/hip_runtime.h>

typedef __bf16 bf16x8 __attribute__((ext_vector_type(8)));
typedef __bf16 bf16x4 __attribute__((ext_vector_type(4)));
typedef float  f32x4  __attribute__((ext_vector_type(4)));

constexpr int B_ = 4, S_ = 1024, D_ = 768, N_ = 12, H_ = 64;
constexpr int BNSH = B_ * N_ * S_ * H_;   // 3,145,728
constexpr float SCALE = 0.125f;           // 1/sqrt(64)

__device__ __forceinline__ f32x4 mfma16(bf16x8 a, bf16x8 b, f32x4 c) {
    return __builtin_amdgcn_mfma_f32_16x16x32_bf16(a, b, c, 0, 0, 0);
}

// async global->LDS, 16B per lane. HW dest = wave-uniform base + lane*16.
__device__ __forceinline__ void gload16(const __bf16* g, __bf16* l) {
    __builtin_amdgcn_global_load_lds(
        (const __attribute__((address_space(1))) unsigned int*)g,
        (__attribute__((address_space(3))) unsigned int*)l, 16, 0, 0);
}

// ---- LDS tile staging with 16B-chunk xor swizzle --------------------------
// Tiles are [rows][64] bf16. Global chunk (r, q) lands at LDS slot (r, q^(r&7)).
// Fragment read of row r, k-chunk c reads slot c^(r&7)  -> 2-way-max conflicts.
__device__ __forceinline__ void stage128x64(const __bf16* g, int ld, __bf16* lds,
                                            int wid, int lane) {
    #pragma unroll
    for (int i = 0; i < 4; ++i) {
        int cb = (wid * 4 + i) * 64;
        int chunk = cb + lane;
        int r = chunk >> 3, p = chunk & 7;
        int q = p ^ (r & 7);
        gload16(g + (size_t)r * ld + q * 8, lds + cb * 8);
    }
}
__device__ __forceinline__ void stage64x64(const __bf16* g, int ld, __bf16* lds,
                                           int wid, int lane) {
    #pragma unroll
    for (int i = 0; i < 2; ++i) {
        int cb = (wid * 2 + i) * 64;
        int chunk = cb + lane;
        int r = chunk >> 3, p = chunk & 7;
        int q = p ^ (r & 7);
        gload16(g + (size_t)r * ld + q * 8, lds + cb * 8);
    }
}
__device__ __forceinline__ bf16x8 frag(const __bf16* lds, int row, int kc) {
    int p = kc ^ (row & 7);
    return *(const bf16x8*)(lds + row * 64 + p * 8);
}

// ---------------------------------------------------------------------------
// Prep kernels: cast / transpose-cast weights to bf16 layouts.
// ---------------------------------------------------------------------------
__global__ __launch_bounds__(256) void cast_x(const float* __restrict__ x,
                                              __bf16* __restrict__ xb) {
    int i = blockIdx.x * 256 + threadIdx.x;      // 786432 float4 groups
    float4 v = ((const float4*)x)[i];
    bf16x4 o;
    o[0] = (__bf16)v.x; o[1] = (__bf16)v.y; o[2] = (__bf16)v.z; o[3] = (__bf16)v.w;
    ((bf16x4*)xb)[i] = o;
}

// W_{Q,K,V}[n][d][h] -> Wt[mat*768 + n*64 + h][d]   ([2304][768] bf16)
__global__ __launch_bounds__(256) void transpose_wqkv(
    const float* __restrict__ wq, const float* __restrict__ wk,
    const float* __restrict__ wv, __bf16* __restrict__ wt) {
    __shared__ __bf16 T[64][65];
    int mat = blockIdx.y / 12, n = blockIdx.y % 12;
    const float* in = (mat == 0 ? wq : mat == 1 ? wk : wv) + (size_t)n * 768 * 64;
    __bf16* out = wt + (size_t)(mat * 768 + n * 64) * 768;
    int d0 = blockIdx.x * 64;
    int tid = threadIdx.x, rr = tid >> 4, c4 = (tid & 15) * 4;
    #pragma unroll
    for (int i = 0; i < 4; ++i) {
        int row = rr + 16 * i;
        float4 v = *(const float4*)&in[(size_t)(d0 + row) * 64 + c4];
        T[c4 + 0][row] = (__bf16)v.x;
        T[c4 + 1][row] = (__bf16)v.y;
        T[c4 + 2][row] = (__bf16)v.z;
        T[c4 + 3][row] = (__bf16)v.w;
    }
    __syncthreads();
    #pragma unroll
    for (int i = 0; i < 4; ++i) {
        int hrow = rr + 16 * i;
        bf16x4 o;
        o[0] = T[hrow][c4 + 0]; o[1] = T[hrow][c4 + 1];
        o[2] = T[hrow][c4 + 2]; o[3] = T[hrow][c4 + 3];
        *(bf16x4*)&out[(size_t)hrow * 768 + d0 + c4] = o;
    }
}

// W_O flat [768][768] -> Wot[dout][k]  ([768][768] bf16)
__global__ __launch_bounds__(256) void transpose_wo(const float* __restrict__ wo,
                                                    __bf16* __restrict__ wot) {
    __shared__ __bf16 T[64][65];
    int r0 = blockIdx.x * 64, c0 = blockIdx.y * 64;
    int tid = threadIdx.x, rr = tid >> 4, c4 = (tid & 15) * 4;
    #pragma unroll
    for (int i = 0; i < 4; ++i) {
        int row = rr + 16 * i;
        float4 v = *(const float4*)&wo[(size_t)(r0 + row) * 768 + c0 + c4];
        T[c4 + 0][row] = (__bf16)v.x;
        T[c4 + 1][row] = (__bf16)v.y;
        T[c4 + 2][row] = (__bf16)v.z;
        T[c4 + 3][row] = (__bf16)v.w;
    }
    __syncthreads();
    #pragma unroll
    for (int i = 0; i < 4; ++i) {
        int crow = rr + 16 * i;
        bf16x4 o;
        o[0] = T[crow][c4 + 0]; o[1] = T[crow][c4 + 1];
        o[2] = T[crow][c4 + 2]; o[3] = T[crow][c4 + 3];
        *(bf16x4*)&wot[(size_t)(c0 + crow) * 768 + r0 + c4] = o;
    }
}

// ---------------------------------------------------------------------------
// QKV GEMM: C[m][j] = x[m][:] . Wt[j][:],  m in [0,4096), j in [0,2304).
// 128x128 tile, BK=64, 4 waves, each wave a 64x64 quadrant of 4x4 MFMA tiles.
// Writes Q,K as [B,N,S,H] bf16; V transposed as [B,N,H,S] bf16.
// ---------------------------------------------------------------------------
__global__ __launch_bounds__(256) void qkv_gemm(
    const __bf16* __restrict__ xb, const __bf16* __restrict__ wtg,
    const float* __restrict__ bq, const float* __restrict__ bk,
    const float* __restrict__ bv,
    __bf16* __restrict__ Qb, __bf16* __restrict__ Kb, __bf16* __restrict__ Vtb) {
    __shared__ __bf16 As[128 * 64];
    __shared__ __bf16 Bs[128 * 64];
    const int m0 = blockIdx.x * 128;
    const int j0 = blockIdx.y * 128;
    const int tid = threadIdx.x, wid = tid >> 6, lane = tid & 63;
    const int quad = lane >> 4, lrow = lane & 15;
    const int wr = wid & 1, wc = wid >> 1;

    f32x4 zf = {0.f, 0.f, 0.f, 0.f};
    f32x4 acc[4][4];
    #pragma unroll
    for (int i = 0; i < 4; ++i)
        #pragma unroll
        for (int j = 0; j < 4; ++j) acc[i][j] = zf;

    for (int kt = 0; kt < 12; ++kt) {
        __syncthreads();
        stage128x64(xb + (size_t)m0 * 768 + kt * 64, 768, As, wid, lane);
        stage128x64(wtg + (size_t)j0 * 768 + kt * 64, 768, Bs, wid, lane);
        __syncthreads();
        #pragma unroll
        for (int ks = 0; ks < 2; ++ks) {
            bf16x8 af[4], bfr[4];
            #pragma unroll
            for (int mi = 0; mi < 4; ++mi)
                af[mi] = frag(As, wr * 64 + mi * 16 + lrow, ks * 4 + quad);
            #pragma unroll
            for (int ni = 0; ni < 4; ++ni)
                bfr[ni] = frag(Bs, wc * 64 + ni * 16 + lrow, ks * 4 + quad);
            #pragma unroll
            for (int mi = 0; mi < 4; ++mi)
                #pragma unroll
                for (int ni = 0; ni < 4; ++ni)
                    acc[mi][ni] = mfma16(af[mi], bfr[ni], acc[mi][ni]);
        }
    }

    // epilogue: decode (mat, n) -- uniform per wave; (b) uniform per block
    const int jw = j0 + wc * 64;
    const int mat = jw / 768;
    const int n = (jw % 768) >> 6;
    const int b = m0 >> 10;
    const int s_base = (m0 & 1023) + wr * 64;
    const float* bias = (mat == 0 ? bq : mat == 1 ? bk : bv) + n * 64;
    float bias_v[4];
    #pragma unroll
    for (int ni = 0; ni < 4; ++ni) bias_v[ni] = bias[ni * 16 + lrow];

    if (mat == 2) {
        __bf16* vout = Vtb + (size_t)(b * N_ + n) * 64 * 1024;
        #pragma unroll
        for (int mi = 0; mi < 4; ++mi)
            #pragma unroll
            for (int ni = 0; ni < 4; ++ni) {
                int h = ni * 16 + lrow;
                int s0 = s_base + mi * 16 + quad * 4;
                bf16x4 pv;
                #pragma unroll
                for (int r = 0; r < 4; ++r)
                    pv[r] = (__bf16)(acc[mi][ni][r] + bias_v[ni]);
                *(bf16x4*)(vout + (size_t)h * 1024 + s0) = pv;
            }
    } else {
        __bf16* qk = (mat == 0 ? Qb : Kb) + (size_t)(b * N_ + n) * 1024 * 64;
        #pragma unroll
        for (int mi = 0; mi < 4; ++mi)
            #pragma unroll
            for (int r = 0; r < 4; ++r) {
                int s = s_base + mi * 16 + quad * 4 + r;
                #pragma unroll
                for (int ni = 0; ni < 4; ++ni) {
                    int h = ni * 16 + lrow;
                    qk[(size_t)s * 64 + h] = (__bf16)(acc[mi][ni][r] + bias_v[ni]);
                }
            }
    }
}

// ---------------------------------------------------------------------------
// Flash attention, bf16 MFMA. One block per (b, n, q-tile of 64).
// Wave w owns q rows [w*16, w*16+16). z written as [B][S][N*H] bf16.
// ---------------------------------------------------------------------------
__global__ __launch_bounds__(256) void attn_mfma(
    const __bf16* __restrict__ Qb, const __bf16* __restrict__ Kb,
    const __bf16* __restrict__ Vtb, __bf16* __restrict__ zb) {
    __shared__ __bf16 Qs[64 * 64], Ks[64 * 64], Vs[64 * 64];
    __shared__ __bf16 Ps[4 * 16 * 64];
    const int bid = blockIdx.x;
    const int qt = bid & 15, n = (bid >> 4) % N_, b = bid / (16 * N_);
    const int tid = threadIdx.x, wid = tid >> 6, lane = tid & 63;
    const int quad = lane >> 4, lrow = lane & 15;
    const __bf16* Qg = Qb + (size_t)(b * N_ + n) * S_ * H_;
    const __bf16* Kg = Kb + (size_t)(b * N_ + n) * S_ * H_;
    const __bf16* Vg = Vtb + (size_t)(b * N_ + n) * H_ * S_;
    const int q0 = qt * 64;

    stage64x64(Qg + (size_t)q0 * 64, 64, Qs, wid, lane);

    f32x4 zf = {0.f, 0.f, 0.f, 0.f};
    f32x4 o[4];
    #pragma unroll
    for (int i = 0; i < 4; ++i) o[i] = zf;
    float m_r[4] = {-1e30f, -1e30f, -1e30f, -1e30f};
    float l_r[4] = {0.f, 0.f, 0.f, 0.f};
    __bf16* Pw = Ps + wid * 16 * 64;
    const int qrow = wid * 16 + lrow;            // A-frag row in Qs
    const int my_q = q0 + wid * 16 + quad * 4;   // +r = absolute q of C-row

    for (int kt = 0; kt <= qt; ++kt) {
        __syncthreads();
        stage64x64(Kg + (size_t)kt * 64 * 64, 64, Ks, wid, lane);
        stage64x64(Vg + kt * 64, 1024, Vs, wid, lane);
        __syncthreads();

        // scores: S[i][kk] for i = this wave's 16 q rows
        f32x4 sc[4];
        #pragma unroll
        for (int i = 0; i < 4; ++i) sc[i] = zf;
        #pragma unroll
        for (int ks = 0; ks < 2; ++ks) {
            bf16x8 aq = frag(Qs, qrow, ks * 4 + quad);
            #pragma unroll
            for (int nt = 0; nt < 4; ++nt) {
                bf16x8 bk8 = frag(Ks, nt * 16 + lrow, ks * 4 + quad);
                sc[nt] = mfma16(aq, bk8, sc[nt]);
            }
        }
        // scale + causal mask (diagonal tile only)
        #pragma unroll
        for (int nt = 0; nt < 4; ++nt)
            #pragma unroll
            for (int r = 0; r < 4; ++r) {
                float v = sc[nt][r] * SCALE;
                if (kt == qt && (kt * 64 + nt * 16 + lrow) > (my_q + r)) v = -1e30f;
                sc[nt][r] = v;
            }
        // online softmax, per C-row (quad*4+r); stats across 16-lane groups
        float alpha[4];
        #pragma unroll
        for (int r = 0; r < 4; ++r) {
            float mt = fmaxf(fmaxf(sc[0][r], sc[1][r]), fmaxf(sc[2][r], sc[3][r]));
            mt = fmaxf(mt, __shfl_xor(mt, 1));
            mt = fmaxf(mt, __shfl_xor(mt, 2));
            mt = fmaxf(mt, __shfl_xor(mt, 4));
            mt = fmaxf(mt, __shfl_xor(mt, 8));
            float mn = fmaxf(m_r[r], mt);
            alpha[r] = __expf(m_r[r] - mn);
            m_r[r] = mn;
            float rs = 0.f;
            #pragma unroll
            for (int nt = 0; nt < 4; ++nt) {
                float p = __expf(sc[nt][r] - mn);
                sc[nt][r] = p;
                rs += p;
            }
            rs += __shfl_xor(rs, 1);
            rs += __shfl_xor(rs, 2);
            rs += __shfl_xor(rs, 4);
            rs += __shfl_xor(rs, 8);
            l_r[r] = l_r[r] * alpha[r] + rs;
        }
        #pragma unroll
        for (int ht = 0; ht < 4; ++ht)
            #pragma unroll
            for (int r = 0; r < 4; ++r) o[ht][r] *= alpha[r];
        // P: C-layout regs -> per-wave LDS strip (swizzled), bf16
        #pragma unroll
        for (int nt = 0; nt < 4; ++nt)
            #pragma unroll
            for (int r = 0; r < 4; ++r) {
                int row = quad * 4 + r, col = nt * 16 + lrow;
                int p = (col >> 3) ^ (row & 7);
                Pw[row * 64 + p * 8 + (col & 7)] = (__bf16)sc[nt][r];
            }
        // PV: O[i][h] += P[i][kk] * Vt[h][kk]
        #pragma unroll
        for (int ks = 0; ks < 2; ++ks) {
            bf16x8 ap = frag(Pw, lrow, ks * 4 + quad);
            #pragma unroll
            for (int ht = 0; ht < 4; ++ht) {
                bf16x8 bv8 = frag(Vs, ht * 16 + lrow, ks * 4 + quad);
                o[ht] = mfma16(ap, bv8, o[ht]);
            }
        }
    }

    __bf16* zout = zb + (size_t)b * S_ * 768 + (size_t)n * 64;
    #pragma unroll
    for (int r = 0; r < 4; ++r) {
        float linv = 1.0f / l_r[r];
        int q = q0 + wid * 16 + quad * 4 + r;
        #pragma unroll
        for (int ht = 0; ht < 4; ++ht)
            zout[(size_t)q * 768 + ht * 16 + lrow] = (__bf16)(o[ht][r] * linv);
    }
}

// ---------------------------------------------------------------------------
// Output projection: out[m][j] = z[m][:] . Wot[j][:] + bo[j]   (fp32 out)
// ---------------------------------------------------------------------------
__global__ __launch_bounds__(256) void out_gemm(
    const __bf16* __restrict__ zb, const __bf16* __restrict__ wot,
    const float* __restrict__ bo, float* __restrict__ out) {
    __shared__ __bf16 As[128 * 64];
    __shared__ __bf16 Bs[128 * 64];
    const int m0 = blockIdx.x * 128;
    const int j0 = blockIdx.y * 128;
    const int tid = threadIdx.x, wid = tid >> 6, lane = tid & 63;
    const int quad = lane >> 4, lrow = lane & 15;
    const int wr = wid & 1, wc = wid >> 1;

    f32x4 zf = {0.f, 0.f, 0.f, 0.f};
    f32x4 acc[4][4];
    #pragma unroll
    for (int i = 0; i < 4; ++i)
        #pragma unroll
        for (int j = 0; j < 4; ++j) acc[i][j] = zf;

    for (int kt = 0; kt < 12; ++kt) {
        __syncthreads();
        stage128x64(zb + (size_t)m0 * 768 + kt * 64, 768, As, wid, lane);
        stage128x64(wot + (size_t)j0 * 768 + kt * 64, 768, Bs, wid, lane);
        __syncthreads();
        #pragma unroll
        for (int ks = 0; ks < 2; ++ks) {
            bf16x8 af[4], bfr[4];
            #pragma unroll
            for (int mi = 0; mi < 4; ++mi)
                af[mi] = frag(As, wr * 64 + mi * 16 + lrow, ks * 4 + quad);
            #pragma unroll
            for (int ni = 0; ni < 4; ++ni)
                bfr[ni] = frag(Bs, wc * 64 + ni * 16 + lrow, ks * 4 + quad);
            #pragma unroll
            for (int mi = 0; mi < 4; ++mi)
                #pragma unroll
                for (int ni = 0; ni < 4; ++ni)
                    acc[mi][ni] = mfma16(af[mi], bfr[ni], acc[mi][ni]);
        }
    }

    float bias_v[4];
    #pragma unroll
    for (int ni = 0; ni < 4; ++ni) bias_v[ni] = bo[j0 + wc * 64 + ni * 16 + lrow];
    #pragma unroll
    for (int mi = 0; mi < 4; ++mi)
        #pragma unroll
        for (int r = 0; r < 4; ++r) {
            int m = m0 + wr * 64 + mi * 16 + quad * 4 + r;
            #pragma unroll
            for (int ni = 0; ni < 4; ++ni) {
                int j = j0 + wc * 64 + ni * 16 + lrow;
                out[(size_t)m * 768 + j] = acc[mi][ni][r] + bias_v[ni];
            }
        }
}

// ---------------------------------------------------------------------------
extern "C" void kernel_launch(void* const* d_in, const int* in_sizes, int n_in,
                              void* d_out, int out_size, void* d_ws, size_t ws_size,
                              hipStream_t stream) {
    const float* x  = (const float*)d_in[0];
    const float* wq = (const float*)d_in[1];
    const float* wk = (const float*)d_in[2];
    const float* wv = (const float*)d_in[3];
    const float* wo = (const float*)d_in[4];
    const float* bq = (const float*)d_in[5];
    const float* bk = (const float*)d_in[6];
    const float* bv = (const float*)d_in[7];
    const float* bo = (const float*)d_in[8];
    float* out = (float*)d_out;

    __bf16* p   = (__bf16*)d_ws;
    __bf16* xb  = p;  p += (size_t)4096 * 768;
    __bf16* wt  = p;  p += (size_t)2304 * 768;
    __bf16* wot = p;  p += (size_t)768 * 768;
    __bf16* Qb  = p;  p += (size_t)BNSH;
    __bf16* Kb  = p;  p += (size_t)BNSH;
    __bf16* Vtb = p;  p += (size_t)BNSH;
    __bf16* zb  = p;  p += (size_t)4096 * 768;

    cast_x<<<3072, 256, 0, stream>>>(x, xb);
    transpose_wqkv<<<dim3(12, 36), 256, 0, stream>>>(wq, wk, wv, wt);
    transpose_wo<<<dim3(12, 12), 256, 0, stream>>>(wo, wot);
    qkv_gemm<<<dim3(32, 18), 256, 0, stream>>>(xb, wt, bq, bk, bv, Qb, Kb, Vtb);
    attn_mfma<<<768, 256, 0, stream>>>(Qb, Kb, Vtb, zb);
    out_gemm<<<dim3(32, 6), 256, 0, stream>>>(zb, wot, bo, out);
}